// Round 2
// baseline (345.017 us; speedup 1.0000x reference)
//
#include <hip/hip_runtime.h>
#include <hip/hip_bf16.h>
#include <stdint.h>

#define NP 409600
#define HG 640
#define WG 640
#define HW (HG*WG)

typedef __bf16 bf16x8 __attribute__((ext_vector_type(8)));
typedef float f32x4 __attribute__((ext_vector_type(4)));

// ---------------- prep kernels ----------------

__global__ void scatter_kernel(const int* __restrict__ coords, int* __restrict__ grid) {
    int i = blockIdx.x * 256 + threadIdx.x;   // grid sized exactly NP
    int b = coords[3*i], y = coords[3*i+1], x = coords[3*i+2];
    grid[b*HW + y*WG + x] = i;
}

__global__ void nbr_kernel(const int* __restrict__ coords, const int* __restrict__ grid,
                           int* __restrict__ nbr) {
    int i = blockIdx.x * 256 + threadIdx.x;
    int b = coords[3*i], y = coords[3*i+1], x = coords[3*i+2];
    int baseg = b*HW;
    #pragma unroll
    for (int t = 0; t < 9; ++t) {
        int ny = y + t/3 - 1, nx = x + t%3 - 1;
        int g = -1;
        if (ny >= 0 && ny < HG && nx >= 0 && nx < WG)
            g = grid[baseg + ny*WG + nx];
        nbr[t*NP + i] = g;
    }
}

__global__ void cast_feat_kernel(const float* __restrict__ f, __hip_bfloat16* __restrict__ fb) {
    long i = (long)(blockIdx.x * 256 + threadIdx.x) * 8;   // grid covers NP*64 exactly
    float4 a = *(const float4*)(f + i);
    float4 b = *(const float4*)(f + i + 4);
    union { uint4 q; __hip_bfloat16 h[8]; } u;
    u.h[0] = __float2bfloat16(a.x); u.h[1] = __float2bfloat16(a.y);
    u.h[2] = __float2bfloat16(a.z); u.h[3] = __float2bfloat16(a.w);
    u.h[4] = __float2bfloat16(b.x); u.h[5] = __float2bfloat16(b.y);
    u.h[6] = __float2bfloat16(b.z); u.h[7] = __float2bfloat16(b.w);
    *(uint4*)(fb + i) = u.q;
}

// weights pre-cast to bf16 and transposed to [tap][n=out_ch][k=in_ch] so
// B-fragments are contiguous 16B LDS reads.
__global__ void cast_w_kernel(const float* __restrict__ w1, const float* __restrict__ w2,
                              const float* __restrict__ wd,
                              __hip_bfloat16* __restrict__ wc1, __hip_bfloat16* __restrict__ wc2) {
    int i = blockIdx.x * 256 + threadIdx.x;   // grid = 77824 threads exactly
    if (i < 9*4096) {
        int t = i >> 12, r = i & 4095, n = r >> 6, k = r & 63;
        wc1[i] = __float2bfloat16(w1[(t << 12) + (k << 6) + n]);
    }
    int j = i - 9*4096;
    if (j >= 0 && j < 10*4096) {
        int t = j >> 12, r = j & 4095, n = r >> 6, k = r & 63;
        float v = (t < 9) ? w2[(t << 12) + (k << 6) + n] : wd[(k << 6) + n];
        wc2[j] = __float2bfloat16(v);
    }
}

// ---------------- gather-GEMM conv kernel ----------------
// Tile: 128 rows x 64 cols per block, 256 threads = 4 waves.
// Wave w computes rows [w*32, w*32+32), all 64 cols, via mfma_f32_16x16x32_bf16.
// A layout: A[m=lane&15][k=quad*8+j]; B layout: B[k=quad*8+j][n=lane&15];
// D layout: D[row=quad*4+reg][col=lane&15].
// LDS rows padded +8 bf16 (stride 72) for bank-conflict reduction.
// FINAL kernel: taps 0..8 = conv2 into acc; tap 9 = identity@wd into accR
// (separate accumulator — reference applies relu(conv2+b2) BEFORE adding
// the residual, so the residual cannot share the accumulator).

#define LDA 72
#define LDB 72

template<int NTAP, bool FINAL>
__launch_bounds__(256)
__global__ void conv_kernel(const __hip_bfloat16* __restrict__ src,    // gather source
                            const __hip_bfloat16* __restrict__ idsrc,  // identity source (FINAL tap)
                            const int* __restrict__ nbr,
                            const __hip_bfloat16* __restrict__ wT,     // [NTAP][64][64] (n,k)
                            const float* __restrict__ bias,
                            __hip_bfloat16* __restrict__ out_bf,
                            float* __restrict__ out_f) {
    __shared__ __align__(16) __hip_bfloat16 As[128 * LDA];
    __shared__ __align__(16) __hip_bfloat16 Bs[64 * LDB];

    const int tid  = threadIdx.x;
    const int base = blockIdx.x * 128;
    const int wave = tid >> 6, lane = tid & 63;
    const int srow = tid >> 1, shalf = tid & 1;   // staging: 2 threads per row

    f32x4 acc[2][4];
    f32x4 accR[2][4];
    #pragma unroll
    for (int i = 0; i < 2; ++i)
        #pragma unroll
        for (int j = 0; j < 4; ++j) {
            acc[i][j]  = (f32x4){0.f, 0.f, 0.f, 0.f};
            accR[i][j] = (f32x4){0.f, 0.f, 0.f, 0.f};
        }

    for (int t = 0; t < NTAP; ++t) {
        if (t) __syncthreads();   // WAR: previous tap's mfma reads done

        // ---- stage A: gather 128 rows x 64 bf16 (zero-fill invalid) ----
        int g;
        const __hip_bfloat16* sp;
        if (FINAL && t == NTAP - 1) { g = base + srow; sp = idsrc; }
        else                        { g = nbr[t*NP + base + srow]; sp = src; }
        uint4 v0, v1, v2, v3;
        if (g >= 0) {
            const uint4* p = (const uint4*)(sp + (long)g*64 + shalf*32);
            v0 = p[0]; v1 = p[1]; v2 = p[2]; v3 = p[3];
        } else {
            v0 = v1 = v2 = v3 = make_uint4(0u, 0u, 0u, 0u);
        }
        uint4* dst = (uint4*)(As + srow*LDA + shalf*32);
        dst[0] = v0; dst[1] = v1; dst[2] = v2; dst[3] = v3;

        // ---- stage B: 64x64 bf16 weight tap ----
        const uint4* wp = (const uint4*)(wT + t*4096);
        #pragma unroll
        for (int j = 0; j < 2; ++j) {
            int e = tid + j*256;          // uint4 index 0..511
            int l = e * 8;
            int n = l >> 6, k = l & 63;
            *(uint4*)(Bs + n*LDB + k) = wp[e];
        }
        __syncthreads();

        // ---- MFMA: K=64 in two k-steps of 32 ----
        auto do_mfma = [&](f32x4 (&ac)[2][4]) {
            #pragma unroll
            for (int ks = 0; ks < 2; ++ks) {
                int kb = ks*32 + (lane >> 4)*8;
                bf16x8 a0 = *(const bf16x8*)(As + (wave*32      + (lane & 15))*LDA + kb);
                bf16x8 a1 = *(const bf16x8*)(As + (wave*32 + 16 + (lane & 15))*LDA + kb);
                bf16x8 b0 = *(const bf16x8*)(Bs + ( 0 + (lane & 15))*LDB + kb);
                bf16x8 b1 = *(const bf16x8*)(Bs + (16 + (lane & 15))*LDB + kb);
                bf16x8 b2 = *(const bf16x8*)(Bs + (32 + (lane & 15))*LDB + kb);
                bf16x8 b3 = *(const bf16x8*)(Bs + (48 + (lane & 15))*LDB + kb);
                ac[0][0] = __builtin_amdgcn_mfma_f32_16x16x32_bf16(a0, b0, ac[0][0], 0, 0, 0);
                ac[0][1] = __builtin_amdgcn_mfma_f32_16x16x32_bf16(a0, b1, ac[0][1], 0, 0, 0);
                ac[0][2] = __builtin_amdgcn_mfma_f32_16x16x32_bf16(a0, b2, ac[0][2], 0, 0, 0);
                ac[0][3] = __builtin_amdgcn_mfma_f32_16x16x32_bf16(a0, b3, ac[0][3], 0, 0, 0);
                ac[1][0] = __builtin_amdgcn_mfma_f32_16x16x32_bf16(a1, b0, ac[1][0], 0, 0, 0);
                ac[1][1] = __builtin_amdgcn_mfma_f32_16x16x32_bf16(a1, b1, ac[1][1], 0, 0, 0);
                ac[1][2] = __builtin_amdgcn_mfma_f32_16x16x32_bf16(a1, b2, ac[1][2], 0, 0, 0);
                ac[1][3] = __builtin_amdgcn_mfma_f32_16x16x32_bf16(a1, b3, ac[1][3], 0, 0, 0);
            }
        };
        if (FINAL && t == NTAP - 1) do_mfma(accR);
        else                        do_mfma(acc);
    }

    // ---- epilogue ----
    const int col = lane & 15, quad = lane >> 4;
    #pragma unroll
    for (int cb = 0; cb < 4; ++cb) {
        float bv = bias[cb*16 + col];
        #pragma unroll
        for (int mb = 0; mb < 2; ++mb) {
            #pragma unroll
            for (int r = 0; r < 4; ++r) {
                float v = acc[mb][cb][r] + bv;
                v = v > 0.f ? v : 0.f;
                long row = base + wave*32 + mb*16 + quad*4 + r;
                int  c   = cb*16 + col;
                if (FINAL) {
                    v += accR[mb][cb][r];      // residual added AFTER inner relu
                    v = v > 0.f ? v : 0.f;
                    out_f[row*64 + c] = v;
                } else {
                    out_bf[row*64 + c] = __float2bfloat16(v);
                }
            }
        }
    }
}

// ---------------- launch ----------------

extern "C" void kernel_launch(void* const* d_in, const int* in_sizes, int n_in,
                              void* d_out, int out_size, void* d_ws, size_t ws_size,
                              hipStream_t stream) {
    const float* features = (const float*)d_in[0];
    const int*   coords   = (const int*)d_in[1];
    const float* w1 = (const float*)d_in[2];
    const float* b1 = (const float*)d_in[3];
    const float* w2 = (const float*)d_in[4];
    const float* b2 = (const float*)d_in[5];
    const float* wd = (const float*)d_in[6];
    float* out = (float*)d_out;

    char* ws = (char*)d_ws;
    int*            grid = (int*)ws;                           // 3,276,800 B
    int*            nbr  = (int*)(ws + 3276800);               // 14,745,600 B
    __hip_bfloat16* fb   = (__hip_bfloat16*)(ws + 18022400);   // 52,428,800 B
    __hip_bfloat16* y1   = (__hip_bfloat16*)(ws + 70451200);   // 52,428,800 B
    __hip_bfloat16* wc1  = (__hip_bfloat16*)(ws + 122880000);  // 73,728 B
    __hip_bfloat16* wc2  = (__hip_bfloat16*)(ws + 122953728);  // 81,920 B
    // total 123,035,648 B

    hipMemsetAsync(grid, 0xFF, (size_t)HW * 2 * sizeof(int), stream);   // grid = -1

    scatter_kernel  <<<1600,  256, 0, stream>>>(coords, grid);
    cast_feat_kernel<<<12800, 256, 0, stream>>>(features, fb);
    cast_w_kernel   <<<304,   256, 0, stream>>>(w1, w2, wd, wc1, wc2);
    nbr_kernel      <<<1600,  256, 0, stream>>>(coords, grid, nbr);

    conv_kernel<9,  false><<<3200, 256, 0, stream>>>(fb, fb, nbr, wc1, b1, y1, nullptr);
    conv_kernel<10, true ><<<3200, 256, 0, stream>>>(y1, fb, nbr, wc2, b2, nullptr, out);
}